// Round 1
// baseline (514.762 us; speedup 1.0000x reference)
//
#include <hip/hip_runtime.h>

// VectorQuantizer: z [16,256,1024] fp32, emb [8192,256] fp32.
// out (FP32): [ z_q 4194304 | loss 1 | idx 16384 ]
// Ref emulation: d = fl(fl(s_z+s_e) - 2p), argmin w/ lowest-index ties.
// Fast path: split-bf16 (hi/lo) MFMA GEMM; A resident in LDS (staged once from z),
// B fragments loaded DIRECTLY from prep'd frag-linear ws into registers
// (double-buffered one kt ahead) -> ZERO barriers in the k-loop.
// Wave tile 64m x 64n (mt=4, nt4=4). Packed-u64 per-64-col cell minima (128
// cells/row) -> ws; pass2 pre-mins cell pairs -> same validated top-4-of-64
// fp64 fixup. Per-dot MFMA op sequence identical to the validated kernel.

#define C_    256
#define T_    1024
#define M_    16384
#define N_    8192

#define OUT_ZQ   0
#define OUT_LOSS 4194304
#define OUT_IDX  4194305

// ---- ws layout, fast path ----
#define WS_SZ    0           // s_z [16384] float
#define WS_SE    16384       // s_e [8192] float
#define WS_PART  24576       // loss partials [256] float   (ends byte 99328)
#define MIN_OFF  131072u     // bytes: u64 minima [16384 rows][128 cells] = 16 MB
#define FB_OFF   16908288u   // bytes: frag-linear emb hi/lo, 8 MB
#define WS_NEED  25296896u   // bytes (< 25.69 MB proven available)
// ---- ws layout, fallback (round-5, known-PASS) ----
#define O_I1     24576
#define O_I2     40960
#define O_PART   73728

typedef __attribute__((ext_vector_type(8))) short bf16x8;
typedef __attribute__((ext_vector_type(4))) float f32x4;
typedef unsigned long long ull;

__device__ __forceinline__ unsigned short f2b(float f) {
    unsigned u = __float_as_uint(f);
    return (unsigned short)((u + 0x7FFFu + ((u >> 16) & 1u)) >> 16);   // RTNE
}
__device__ __forceinline__ float b2f(unsigned short u) {
    return __uint_as_float(((unsigned)u) << 16);
}

// ---------------- s_z / s_e: numpy pairwise_sum replication ----------------
__global__ __launch_bounds__(256) void vq_sums(const float* __restrict__ z,
                                               const float* __restrict__ emb,
                                               float* __restrict__ ws) {
    int gid = blockIdx.x * 256 + threadIdx.x;
    if (gid < M_) {
        int b = gid >> 10, t = gid & (T_ - 1);
        const float* zp = z + (size_t)b * C_ * T_ + t;
        float blk[2];
#pragma unroll
        for (int h = 0; h < 2; ++h) {
            float r[8];
#pragma unroll
            for (int j = 0; j < 8; ++j) {
                float v = zp[(size_t)(h * 128 + j) * T_];
                r[j] = __fmul_rn(v, v);
            }
            for (int i = 8; i < 128; i += 8)
#pragma unroll
                for (int j = 0; j < 8; ++j) {
                    float v = zp[(size_t)(h * 128 + i + j) * T_];
                    r[j] = __fadd_rn(r[j], __fmul_rn(v, v));
                }
            blk[h] = __fadd_rn(__fadd_rn(__fadd_rn(r[0], r[1]), __fadd_rn(r[2], r[3])),
                               __fadd_rn(__fadd_rn(r[4], r[5]), __fadd_rn(r[6], r[7])));
        }
        ws[WS_SZ + gid] = __fadd_rn(blk[0], blk[1]);
    } else if (gid < M_ + N_) {
        int n = gid - M_;
        const float* ep = emb + (size_t)n * C_;
        float blk[2];
#pragma unroll
        for (int h = 0; h < 2; ++h) {
            float r[8];
#pragma unroll
            for (int j = 0; j < 8; ++j) {
                float v = ep[h * 128 + j];
                r[j] = __fmul_rn(v, v);
            }
            for (int i = 8; i < 128; i += 8)
#pragma unroll
                for (int j = 0; j < 8; ++j) {
                    float v = ep[h * 128 + i + j];
                    r[j] = __fadd_rn(r[j], __fmul_rn(v, v));
                }
            blk[h] = __fadd_rn(__fadd_rn(__fadd_rn(r[0], r[1]), __fadd_rn(r[2], r[3])),
                               __fadd_rn(__fadd_rn(r[4], r[5]), __fadd_rn(r[6], r[7])));
        }
        ws[WS_SE + n] = __fadd_rn(blk[0], blk[1]);
    }
}

// ---------------- prep: emb -> frag-linear bf16 hi/lo (fb) ----------------
__global__ __launch_bounds__(256) void vq_prep_b(const float* __restrict__ emb,
                                                 char* __restrict__ fb) {
    int gid = blockIdx.x * 256 + threadIdx.x;     // 262144
    int n = gid >> 5, kg = gid & 31;
    const float* ep = emb + (size_t)n * C_ + kg * 8;
    unsigned hi[8], lo[8];
#pragma unroll
    for (int j = 0; j < 8; ++j) {
        float v = ep[j];
        unsigned short h = f2b(v);
        hi[j] = h;
        lo[j] = f2b(v - b2f(h));
    }
    int nt = n >> 4, kt = kg >> 2, lane = (kg & 3) * 16 + (n & 15);
    size_t base = ((size_t)((nt * 8 + kt) * 2) << 10) + (lane << 4);
    uint4 hv = {hi[0] | (hi[1] << 16), hi[2] | (hi[3] << 16), hi[4] | (hi[5] << 16), hi[6] | (hi[7] << 16)};
    uint4 lv = {lo[0] | (lo[1] << 16), lo[2] | (lo[3] << 16), lo[4] | (lo[5] << 16), lo[6] | (lo[7] << 16)};
    *(uint4*)(fb + base) = hv;
    *(uint4*)(fb + base + 1024) = lv;
}

// ---------------- pass1: MFMA GEMM, A resident, B reg-streamed, barrier-free k-loop ----
// grid 512 linear (XCD-clustered: XCDs 0-3 -> ns=0, 4-7 -> ns=1), block 256 (4 waves,
// each wave = 64m x 64n of the block's 64m x 256n nt-tile).
__global__ __launch_bounds__(256, 2) void vq_mfma3(
        const float* __restrict__ z, const char* __restrict__ fb,
        const float* __restrict__ sz, const float* __restrict__ se,
        ull* __restrict__ minima) {
    __shared__ __align__(16) char ldsA[65536];   // 64m x 256k hi/lo, frag-linear

    const int tid = threadIdx.x;
    const int lane = tid & 63;
    const int w = tid >> 6;                      // wave -> n-quarter
    const int quad = lane >> 4, li = lane & 15;

    // XCD-aware decode: round-robin dispatch puts bid&7 on XCD (bid&7);
    // cluster ns halves so each XCD's L2 holds one 4 MB fb half.
    const int bid = blockIdx.x;
    const int ns = (bid >> 2) & 1;
    const int mb = ((bid >> 3) << 2) | (bid & 3);

    // ---- one-time A staging: z[b][c][t0..t0+64) -> hi/lo frag-linear LDS ----
    {
        const float* zb = z + (size_t)(mb >> 4) * C_ * T_ + ((mb & 15) << 6);
#pragma unroll
        for (int p = 0; p < 4; ++p) {
            int c  = p * 64 + (tid >> 2);
            int tq = tid & 3;
            const float* src = zb + (size_t)c * T_ + tq * 16;
            int kt = c >> 5, kg3 = (c >> 3) & 3, j = c & 7;
            unsigned short* d0 = (unsigned short*)(ldsA + (((tq * 8 + kt) * 2 + 0) << 10) + (kg3 << 8) + (j << 1));
            unsigned short* d1 = (unsigned short*)(ldsA + (((tq * 8 + kt) * 2 + 1) << 10) + (kg3 << 8) + (j << 1));
#pragma unroll
            for (int u = 0; u < 4; ++u) {
                float4 v = *(const float4*)(src + u * 4);
                float vv[4] = {v.x, v.y, v.z, v.w};
#pragma unroll
                for (int e = 0; e < 4; ++e) {
                    unsigned short h = f2b(vv[e]);
                    unsigned short l = f2b(vv[e] - b2f(h));
                    int i = u * 4 + e;
                    d0[i * 8] = h;            // i*16 bytes
                    d1[i * 8] = l;
                }
            }
        }
    }
    __syncthreads();                          // ONLY barrier; k-loop is barrier-free

    float szr[16];
#pragma unroll
    for (int mt = 0; mt < 4; ++mt)
#pragma unroll
        for (int r = 0; r < 4; ++r)
            szr[mt * 4 + r] = sz[(mb << 6) + (mt << 4) + (quad << 2) + r];

    const char* fbw = fb + (lane << 4);       // per-lane fragment base

#define LOADB(dst, kt_) do {                                                          \
    _Pragma("unroll")                                                                 \
    for (int nt4_ = 0; nt4_ < 4; ++nt4_) {                                            \
        _Pragma("unroll")                                                             \
        for (int p_ = 0; p_ < 2; ++p_)                                                \
            dst[nt4_ * 2 + p_] = *(const bf16x8*)(fbw +                               \
                ((((ntile0 + nt4_) * 8 + (kt_)) * 2 + p_) << 10));                    \
    }                                                                                 \
} while (0)

#define COMPUTE(kt_, bb) do {                                                         \
    _Pragma("unroll")                                                                 \
    for (int mt_ = 0; mt_ < 4; ++mt_) {                                               \
        bf16x8 ah = *(const bf16x8*)(ldsA + (((mt_ * 8 + (kt_)) * 2 + 0) << 10) + (lane << 4)); \
        bf16x8 al = *(const bf16x8*)(ldsA + (((mt_ * 8 + (kt_)) * 2 + 1) << 10) + (lane << 4)); \
        _Pragma("unroll")                                                             \
        for (int nt4_ = 0; nt4_ < 4; ++nt4_) {                                        \
            f32x4 c = acc[mt_][nt4_];                                                 \
            c = __builtin_amdgcn_mfma_f32_16x16x32_bf16(ah, bb[nt4_ * 2 + 0], c, 0, 0, 0); \
            c = __builtin_amdgcn_mfma_f32_16x16x32_bf16(ah, bb[nt4_ * 2 + 1], c, 0, 0, 0); \
            c = __builtin_amdgcn_mfma_f32_16x16x32_bf16(al, bb[nt4_ * 2 + 0], c, 0, 0, 0); \
            acc[mt_][nt4_] = c;                                                       \
        }                                                                             \
    }                                                                                 \
} while (0)

    for (int nt = 0; nt < 16; ++nt) {
        const int ntile0 = ns * 256 + (nt << 4) + (w << 2);   // n-tile-of-16 base
        f32x4 acc[4][4];
#pragma unroll
        for (int i = 0; i < 4; ++i)
#pragma unroll
            for (int j = 0; j < 4; ++j) acc[i][j] = (f32x4){0.f, 0.f, 0.f, 0.f};

        bf16x8 bA[8], bB[8];
        LOADB(bA, 0);
#pragma unroll
        for (int kth = 0; kth < 4; ++kth) {
            LOADB(bB, 2 * kth + 1);           // prefetch odd kt
            COMPUTE(2 * kth, bA);
            if (kth < 3) LOADB(bA, 2 * kth + 2);  // prefetch next even kt
            COMPUTE(2 * kth + 1, bB);
        }

        // epilogue: quantized ref-formula score -> per-(row,64-col-cell) u64 min
        float sev[4];
#pragma unroll
        for (int nt4 = 0; nt4 < 4; ++nt4)
            sev[nt4] = se[((ntile0 + nt4) << 4) + li];
#pragma unroll
        for (int mt = 0; mt < 4; ++mt) {
#pragma unroll
            for (int r = 0; r < 4; ++r) {
                ull best = ~0ULL;
#pragma unroll
                for (int nt4 = 0; nt4 < 4; ++nt4) {
                    const int ncol = ((ntile0 + nt4) << 4) + li;
                    float s = fmaf(-2.f, acc[mt][nt4][r], __fadd_rn(szr[mt * 4 + r], sev[nt4]));
                    ull k = ((ull)__float_as_uint(s) << 32) | (unsigned)ncol;
                    if (k < best) best = k;
                }
#pragma unroll
                for (int off = 1; off <= 8; off <<= 1) {
                    ull o = __shfl_xor(best, off, 64);
                    if (o < best) best = o;
                }
                if (li == 0) {
                    int row = (mb << 6) + (mt << 4) + (quad << 2) + r;
                    minima[(size_t)row * 128 + (ns << 6) + (nt << 2) + w] = best;
                }
            }
        }
    }
#undef LOADB
#undef COMPUTE
}

// ---------------- pass2: top-4 of 128 cells (pair-preminned) + fp64 fixup + idx out ----
// grid 1024, block 256; block owns 16 consecutive rows (z tile staged in LDS).
__global__ __launch_bounds__(256) void vq_pick2(
        const float* __restrict__ z, const float* __restrict__ emb,
        const float* __restrict__ ws, const ull* __restrict__ minima,
        float* __restrict__ out) {
    __shared__ float Lz[256 * 17];            // [c][t0..15], padded
    const float* sz = ws + WS_SZ;
    const float* se = ws + WS_SE;
    const int tid = threadIdx.x;
    const int w = tid >> 6, lane = tid & 63, li = lane & 15;
    const int m0 = blockIdx.x * 16;
    const int b = m0 >> 10, t0 = m0 & (T_ - 1);

    {   // stage z tile: 16 t x 256 c
        const float* src = z + (size_t)b * C_ * T_ + (size_t)tid * T_ + t0;
#pragma unroll
        for (int u = 0; u < 4; ++u) {
            float4 v = *(const float4*)(src + u * 4);
            Lz[tid * 17 + u * 4 + 0] = v.x;
            Lz[tid * 17 + u * 4 + 1] = v.y;
            Lz[tid * 17 + u * 4 + 2] = v.z;
            Lz[tid * 17 + u * 4 + 3] = v.w;
        }
    }
    __syncthreads();

    for (int rr = 0; rr < 4; ++rr) {
        const int tloc = w * 4 + rr;
        const int m = m0 + tloc;
        // pre-min cell pairs (c, c+64) -> 64 jittered cell-minima, then top-4
        ull k0 = minima[(size_t)m * 128 + lane];
        ull k1 = minima[(size_t)m * 128 + 64 + lane];
        ull kmin = k1 < k0 ? k1 : k0;
        int cand[4];
#pragma unroll
        for (int rep = 0; rep < 4; ++rep) {
            ull bf = kmin;
#pragma unroll
            for (int off = 1; off <= 32; off <<= 1) {
                ull o = __shfl_xor(bf, off, 64);
                if (o < bf) bf = o;
            }
            int ix = (int)(unsigned)(bf & 0xFFFFFFFFull);
            cand[rep] = ix < 0 ? 0 : (ix > N_ - 1 ? N_ - 1 : ix);
            if (kmin == bf) kmin = ~0ULL;
        }
        // fp64 dots: 4 groups of 16 lanes, one candidate each
        const int cn = cand[lane >> 4];
        const float* ep = emb + (size_t)cn * C_;
        double sum = 0.0;
#pragma unroll
        for (int cc = 0; cc < 16; ++cc) {
            int c = cc * 16 + li;
            sum = fma((double)Lz[c * 17 + tloc], (double)ep[c], sum);
        }
#pragma unroll
        for (int off = 1; off <= 8; off <<= 1)
            sum += __shfl_xor(sum, off, 64);
        double s0 = __shfl(sum, 0, 64), s1 = __shfl(sum, 16, 64);
        double s2 = __shfl(sum, 32, 64), s3 = __shfl(sum, 48, 64);
        if (lane == 0) {
            float szm = sz[m];
            float d0 = fmaf(-2.f, (float)s0, __fadd_rn(szm, se[cand[0]]));
            float d1 = fmaf(-2.f, (float)s1, __fadd_rn(szm, se[cand[1]]));
            float d2 = fmaf(-2.f, (float)s2, __fadd_rn(szm, se[cand[2]]));
            float d3 = fmaf(-2.f, (float)s3, __fadd_rn(szm, se[cand[3]]));
            float bd = d0; int bi = cand[0];
            if (d1 < bd || (d1 == bd && cand[1] < bi)) { bd = d1; bi = cand[1]; }
            if (d2 < bd || (d2 == bd && cand[2] < bi)) { bd = d2; bi = cand[2]; }
            if (d3 < bd || (d3 == bd && cand[3] < bi)) { bd = d3; bi = cand[3]; }
            out[OUT_IDX + m] = (float)bi;
        }
    }
}

// ---------------- fallback round-5 pass1/pass2 (known-PASS) ----------------
__global__ __launch_bounds__(256) void vq_pass1_fp32(
        const float* __restrict__ z,
        const float* __restrict__ emb,
        float* __restrict__ ws) {
    __shared__ float As[32][68];
    __shared__ float Bs[32][68];
    const float* s_z = ws + WS_SZ;
    const float* s_e = ws + WS_SE;
    int* i1ws = (int*)ws + O_I1;
    int* i2ws = (int*)ws + O_I2;
    const int tid = threadIdx.x;
    const int mt  = blockIdx.x;
    const int tx  = tid & 15, ty = tid >> 4;
    const int b   = mt >> 4;
    const int t0  = (mt << 6) & (T_ - 1);
    const float* zbase = z + (size_t)b * C_ * T_ + t0;
    const int a_k = tid >> 4;
    const int a_m = (tid & 15) << 2;
    const int b_j = tid >> 2;
    const int b_q = (tid & 3) << 3;
    const float4 sz4 = *(const float4*)(s_z + mt * 64 + (ty << 2));
    const float szv[4] = {sz4.x, sz4.y, sz4.z, sz4.w};
    float v1[4], v2[4];
    int   i1[4], i2[4];
#pragma unroll
    for (int i = 0; i < 4; ++i) {
        v1[i] = INFINITY; v2[i] = INFINITY;
        i1[i] = 0x7FFFFFFF; i2[i] = 0x7FFFFFFF;
    }
    for (int nt = 0; nt < N_ / 64; ++nt) {
        const int n0 = nt * 64;
        float acc[4][4];
#pragma unroll
        for (int i = 0; i < 4; ++i)
#pragma unroll
            for (int j = 0; j < 4; ++j) acc[i][j] = 0.f;
        for (int kt = 0; kt < C_; kt += 32) {
            __syncthreads();
#pragma unroll
            for (int p = 0; p < 2; ++p) {
                int k = a_k + p * 16;
                float4 af = *(const float4*)(zbase + (size_t)(kt + k) * T_ + a_m);
                *(float4*)&As[k][a_m] = af;
            }
            {
                const float* ep = emb + (size_t)(n0 + b_j) * C_ + kt + b_q;
                float4 e0 = ((const float4*)ep)[0];
                float4 e1 = ((const float4*)ep)[1];
                Bs[b_q + 0][b_j] = e0.x; Bs[b_q + 1][b_j] = e0.y;
                Bs[b_q + 2][b_j] = e0.z; Bs[b_q + 3][b_j] = e0.w;
                Bs[b_q + 4][b_j] = e1.x; Bs[b_q + 5][b_j] = e1.y;
                Bs[b_q + 6][b_j] = e1.z; Bs[b_q + 7][b_j] = e1.w;
            }
            __syncthreads();
#pragma unroll
            for (int k = 0; k < 32; ++k) {
                const float4 a  = *(const float4*)&As[k][ty << 2];
                const float4 bv = *(const float4*)&Bs[k][tx << 2];
                acc[0][0] = fmaf(a.x, bv.x, acc[0][0]);
                acc[0][1] = fmaf(a.x, bv.y, acc[0][1]);
                acc[0][2] = fmaf(a.x, bv.z, acc[0][2]);
                acc[0][3] = fmaf(a.x, bv.w, acc[0][3]);
                acc[1][0] = fmaf(a.y, bv.x, acc[1][0]);
                acc[1][1] = fmaf(a.y, bv.y, acc[1][1]);
                acc[1][2] = fmaf(a.y, bv.z, acc[1][2]);
                acc[1][3] = fmaf(a.y, bv.w, acc[1][3]);
                acc[2][0] = fmaf(a.z, bv.x, acc[2][0]);
                acc[2][1] = fmaf(a.z, bv.y, acc[2][1]);
                acc[2][2] = fmaf(a.z, bv.z, acc[2][2]);
                acc[2][3] = fmaf(a.z, bv.w, acc[2][3]);
                acc[3][0] = fmaf(a.w, bv.x, acc[3][0]);
                acc[3][1] = fmaf(a.w, bv.y, acc[3][1]);
                acc[3][2] = fmaf(a.w, bv.z, acc[3][2]);
                acc[3][3] = fmaf(a.w, bv.w, acc[3][3]);
            }
        }
        const float4 se4 = *(const float4*)(s_e + n0 + (tx << 2));
        const float sev[4] = {se4.x, se4.y, se4.z, se4.w};
#pragma unroll
        for (int j = 0; j < 4; ++j) {
            const int n = n0 + (tx << 2) + j;
#pragma unroll
            for (int i = 0; i < 4; ++i) {
                float A = __fadd_rn(szv[i], sev[j]);
                float s = fmaf(-2.f, acc[i][j], A);
                if (s < v1[i]) { v2[i] = v1[i]; i2[i] = i1[i]; v1[i] = s; i1[i] = n; }
                else if (s < v2[i]) { v2[i] = s; i2[i] = n; }
            }
        }
    }
#pragma unroll
    for (int i = 0; i < 4; ++i) {
        float a1 = v1[i], a2 = v2[i];
        int   y1 = i1[i], y2 = i2[i];
#pragma unroll
        for (int off = 8; off >= 1; off >>= 1) {
            float o1 = __shfl_xor(a1, off, 64); int p1 = __shfl_xor(y1, off, 64);
            float o2 = __shfl_xor(a2, off, 64); int p2 = __shfl_xor(y2, off, 64);
            bool alt = (o1 < a1) || (o1 == a1 && p1 < y1);
            float w1 = alt ? o1 : a1; int q1 = alt ? p1 : y1;
            float lv = alt ? a1 : o1; int lq = alt ? y1 : p1;
            float wv = alt ? o2 : a2; int wq = alt ? p2 : y2;
            bool sb = (lv < wv) || (lv == wv && lq < wq);
            a2 = sb ? lv : wv; y2 = sb ? lq : wq;
            a1 = w1; y1 = q1;
        }
        if (tx == 0) {
            int m = mt * 64 + (ty << 2) + i;
            i1ws[m] = y1;
            i2ws[m] = y2;
        }
    }
}

__global__ __launch_bounds__(256) void vq_pass2_fp32(
        const float* __restrict__ z,
        const float* __restrict__ emb,
        float* __restrict__ ws,
        float* __restrict__ out) {
    const float* s_z = ws + WS_SZ;
    const float* s_e = ws + WS_SE;
    const int* i1ws = (const int*)ws + O_I1;
    const int* i2ws = (const int*)ws + O_I2;
    const int tid  = threadIdx.x;
    const int wave = tid >> 6, lane = tid & 63;
    const int half = lane >> 5;
    const int c0   = (lane & 31) << 3;
    const int rowbase = (blockIdx.x * 4 + wave) * 64;
    for (int r = 0; r < 64; ++r) {
        const int m = rowbase + r;
        int c1 = i1ws[m], c2 = i2ws[m];
        c1 = c1 < 0 ? 0 : (c1 > N_ - 1 ? N_ - 1 : c1);
        c2 = c2 < 0 ? 0 : (c2 > N_ - 1 ? N_ - 1 : c2);
        const int b = m >> 10, t = m & (T_ - 1);
        const float* zp = z + (size_t)b * C_ * T_ + t;
        const int cand = half ? c2 : c1;
        const float* ep = emb + (size_t)cand * C_;
        double sum = 0.0;
#pragma unroll
        for (int c = 0; c < 8; ++c)
            sum = fma((double)zp[(size_t)(c0 + c) * T_], (double)ep[c0 + c], sum);
#pragma unroll
        for (int off = 1; off <= 16; off <<= 1)
            sum += __shfl_xor(sum, off, 64);
        double s1 = __shfl(sum, 0, 64);
        double s2 = __shfl(sum, 32, 64);
        if (lane == 0) {
            float p1 = (float)s1, p2 = (float)s2;
            float d1 = fmaf(-2.f, p1, __fadd_rn(s_z[m], s_e[c1]));
            float d2 = fmaf(-2.f, p2, __fadd_rn(s_z[m], s_e[c2]));
            int win = ((d2 < d1) || (d2 == d1 && c2 < c1)) ? c2 : c1;
            out[OUT_IDX + m] = (float)win;
        }
    }
}

// ---------------- gather z_q (transposed) + loss partial; idx from out ----------------
__global__ __launch_bounds__(256) void vq_gather(
        const float* __restrict__ z,
        const float* __restrict__ emb,
        float* __restrict__ partial,
        float* __restrict__ out) {
    __shared__ float Ls[64][129];
    __shared__ int   idxs[64];
    __shared__ float wred[4];
    const int tid = threadIdx.x;
    const int mg  = blockIdx.x;
    const int m0  = mg << 6;
    const int b   = m0 >> 10;
    const int t0  = m0 & (T_ - 1);
    if (tid < 64) {
        int ix = (int)out[OUT_IDX + m0 + tid];
        idxs[tid] = ix < 0 ? 0 : (ix > N_ - 1 ? N_ - 1 : ix);
    }
    __syncthreads();
    float lsum = 0.f;
    const int w = tid >> 6, l = tid & 63;
    const int tt2 = tid & 63, c0 = tid >> 6;
    const size_t base = (size_t)b * (C_ * T_) + t0 + tt2;
#pragma unroll
    for (int ch = 0; ch < 2; ++ch) {
        __syncthreads();
#pragma unroll
        for (int it = 0; it < 8; ++it) {
            int tt = it * 8 + w * 2 + (l >> 5);
            int cq = l & 31;
            int row = idxs[tt];
            float4 ev = *(const float4*)(emb + (size_t)row * C_ + ch * 128 + (cq << 2));
            Ls[tt][(cq << 2) + 0] = ev.x;
            Ls[tt][(cq << 2) + 1] = ev.y;
            Ls[tt][(cq << 2) + 2] = ev.z;
            Ls[tt][(cq << 2) + 3] = ev.w;
        }
        __syncthreads();
#pragma unroll
        for (int st = 0; st < 32; ++st) {
            int c_l = (st << 2) + c0;
            int c   = (ch << 7) + c_l;
            float v = Ls[tt2][c_l];
            size_t off = base + (size_t)c * T_;
            out[OUT_ZQ + off] = v;
            float d = v - z[off];
            lsum = fmaf(d, d, lsum);
        }
    }
#pragma unroll
    for (int off = 32; off >= 1; off >>= 1) lsum += __shfl_xor(lsum, off, 64);
    if (l == 0) wred[w] = lsum;
    __syncthreads();
    if (tid == 0) partial[mg] = wred[0] + wred[1] + wred[2] + wred[3];
}

__global__ __launch_bounds__(256) void vq_loss(const float* __restrict__ partial,
                                               float* __restrict__ out) {
    __shared__ float wred[4];
    const int tid = threadIdx.x;
    float v = partial[tid];
#pragma unroll
    for (int off = 32; off >= 1; off >>= 1) v += __shfl_xor(v, off, 64);
    if ((tid & 63) == 0) wred[tid >> 6] = v;
    __syncthreads();
    if (tid == 0)
        out[OUT_LOSS] = (wred[0] + wred[1] + wred[2] + wred[3]) * (1.25f / 4194304.f);
}

extern "C" void kernel_launch(void* const* d_in, const int* in_sizes, int n_in,
                              void* d_out, int out_size, void* d_ws, size_t ws_size,
                              hipStream_t stream) {
    const float* z   = (const float*)d_in[0];
    const float* emb = (const float*)d_in[1];
    float* out = (float*)d_out;
    float* ws  = (float*)d_ws;

    vq_sums<<<dim3((M_ + N_) / 256), dim3(256), 0, stream>>>(z, emb, ws);

    if (ws_size >= WS_NEED) {   // fast MFMA path
        char* fb = (char*)d_ws + FB_OFF;
        ull* minima = (ull*)((char*)d_ws + MIN_OFF);
        vq_prep_b<<<dim3(1024), dim3(256), 0, stream>>>(emb, fb);
        vq_mfma3<<<dim3(512), dim3(256), 0, stream>>>(z, fb, ws + WS_SZ, ws + WS_SE, minima);
        vq_pick2<<<dim3(1024), dim3(256), 0, stream>>>(z, emb, ws, minima, out);
        vq_gather<<<dim3(M_ / 64), dim3(256), 0, stream>>>(z, emb, ws + WS_PART, out);
        vq_loss<<<dim3(1), dim3(256), 0, stream>>>(ws + WS_PART, out);
    } else {                    // round-5 fallback (known-PASS)
        vq_pass1_fp32<<<dim3(M_ / 64), dim3(256), 0, stream>>>(z, emb, ws);
        vq_pass2_fp32<<<dim3(64), dim3(256), 0, stream>>>(z, emb, ws, out);
        vq_gather<<<dim3(M_ / 64), dim3(256), 0, stream>>>(z, emb, ws + O_PART, out);
        vq_loss<<<dim3(1), dim3(256), 0, stream>>>(ws + O_PART, out);
    }
}

// Round 2
// 354.725 us; speedup vs baseline: 1.4512x; 1.4512x over previous
//
#include <hip/hip_runtime.h>

// VectorQuantizer: z [16,256,1024] fp32, emb [8192,256] fp32.
// out (FP32): [ z_q 4194304 | loss 1 | idx 16384 ]
// Ref emulation: d = fl(fl(s_z+s_e) - 2p), argmin w/ lowest-index ties.
// Fast path: split-bf16 (hi/lo) MFMA GEMM; A resident in LDS (staged once from z),
// B staged per-kt via async global_load_lds into a double-buffered LDS tile
// (2-phase pipeline: issue kt+1 loads, compute kt, one barrier per phase).
// Wave tile 64m x 64n (mt=4, nt4=4): per CU per phase MFMA 931cy > LDS 750cy
// -> MFMA-bound. 64-cell minima (128-col cells) -> validated top-4-of-64
// fp64 fixup. Per-dot MFMA op sequence identical to the validated kernel.

#define C_    256
#define T_    1024
#define M_    16384
#define N_    8192

#define OUT_ZQ   0
#define OUT_LOSS 4194304
#define OUT_IDX  4194305

// ---- ws layout, fast path ----
#define WS_SZ    0           // s_z [16384] float
#define WS_SE    16384       // s_e [8192] float
#define WS_PART  24576       // loss partials [256] float   (ends byte 99328)
#define MIN_OFF  131072u     // bytes: u64 minima [16384 rows][64 cells] = 8 MB
#define FB_OFF   8519680u    // bytes: frag-linear emb hi/lo, 8 MB
#define WS_NEED  16908288u   // bytes (< 25.69 MB proven available)
// ---- ws layout, fallback (round-5, known-PASS) ----
#define O_I1     24576
#define O_I2     40960
#define O_PART   73728

typedef __attribute__((ext_vector_type(8))) short bf16x8;
typedef __attribute__((ext_vector_type(4))) float f32x4;
typedef unsigned long long ull;

__device__ __forceinline__ unsigned short f2b(float f) {
    unsigned u = __float_as_uint(f);
    return (unsigned short)((u + 0x7FFFu + ((u >> 16) & 1u)) >> 16);   // RTNE
}
__device__ __forceinline__ float b2f(unsigned short u) {
    return __uint_as_float(((unsigned)u) << 16);
}

// ---------------- s_z / s_e: numpy pairwise_sum replication ----------------
__global__ __launch_bounds__(256) void vq_sums(const float* __restrict__ z,
                                               const float* __restrict__ emb,
                                               float* __restrict__ ws) {
    int gid = blockIdx.x * 256 + threadIdx.x;
    if (gid < M_) {
        int b = gid >> 10, t = gid & (T_ - 1);
        const float* zp = z + (size_t)b * C_ * T_ + t;
        float blk[2];
#pragma unroll
        for (int h = 0; h < 2; ++h) {
            float r[8];
#pragma unroll
            for (int j = 0; j < 8; ++j) {
                float v = zp[(size_t)(h * 128 + j) * T_];
                r[j] = __fmul_rn(v, v);
            }
            for (int i = 8; i < 128; i += 8)
#pragma unroll
                for (int j = 0; j < 8; ++j) {
                    float v = zp[(size_t)(h * 128 + i + j) * T_];
                    r[j] = __fadd_rn(r[j], __fmul_rn(v, v));
                }
            blk[h] = __fadd_rn(__fadd_rn(__fadd_rn(r[0], r[1]), __fadd_rn(r[2], r[3])),
                               __fadd_rn(__fadd_rn(r[4], r[5]), __fadd_rn(r[6], r[7])));
        }
        ws[WS_SZ + gid] = __fadd_rn(blk[0], blk[1]);
    } else if (gid < M_ + N_) {
        int n = gid - M_;
        const float* ep = emb + (size_t)n * C_;
        float blk[2];
#pragma unroll
        for (int h = 0; h < 2; ++h) {
            float r[8];
#pragma unroll
            for (int j = 0; j < 8; ++j) {
                float v = ep[h * 128 + j];
                r[j] = __fmul_rn(v, v);
            }
            for (int i = 8; i < 128; i += 8)
#pragma unroll
                for (int j = 0; j < 8; ++j) {
                    float v = ep[h * 128 + i + j];
                    r[j] = __fadd_rn(r[j], __fmul_rn(v, v));
                }
            blk[h] = __fadd_rn(__fadd_rn(__fadd_rn(r[0], r[1]), __fadd_rn(r[2], r[3])),
                               __fadd_rn(__fadd_rn(r[4], r[5]), __fadd_rn(r[6], r[7])));
        }
        ws[WS_SE + n] = __fadd_rn(blk[0], blk[1]);
    }
}

// ---------------- prep: emb -> frag-linear bf16 hi/lo (fb) ----------------
__global__ __launch_bounds__(256) void vq_prep_b(const float* __restrict__ emb,
                                                 char* __restrict__ fb) {
    int gid = blockIdx.x * 256 + threadIdx.x;     // 262144
    int n = gid >> 5, kg = gid & 31;
    const float* ep = emb + (size_t)n * C_ + kg * 8;
    unsigned hi[8], lo[8];
#pragma unroll
    for (int j = 0; j < 8; ++j) {
        float v = ep[j];
        unsigned short h = f2b(v);
        hi[j] = h;
        lo[j] = f2b(v - b2f(h));
    }
    int nt = n >> 4, kt = kg >> 2, lane = (kg & 3) * 16 + (n & 15);
    size_t base = ((size_t)((nt * 8 + kt) * 2) << 10) + (lane << 4);
    uint4 hv = {hi[0] | (hi[1] << 16), hi[2] | (hi[3] << 16), hi[4] | (hi[5] << 16), hi[6] | (hi[7] << 16)};
    uint4 lv = {lo[0] | (lo[1] << 16), lo[2] | (lo[3] << 16), lo[4] | (lo[5] << 16), lo[6] | (lo[7] << 16)};
    *(uint4*)(fb + base) = hv;
    *(uint4*)(fb + base + 1024) = lv;
}

// ---------------- pass1: MFMA GEMM, A resident, B async double-buffered ----------------
// grid (256 m-blocks, 2 ns), block 256 (4 waves, each 64m x 64n of the 64m x 256n tile).
__global__ __launch_bounds__(256, 1) void vq_mfma4(
        const float* __restrict__ z, const char* __restrict__ fb,
        const float* __restrict__ sz, const float* __restrict__ se,
        ull* __restrict__ minima) {
    __shared__ __align__(16) char ldsA[65536];   // 64m x 256k hi/lo, frag-linear
    __shared__ __align__(16) char ldsB[65536];   // 2 x (256n x 32k hi/lo) double buffer

    const int tid = threadIdx.x;
    const int lane = tid & 63;
    const int w = tid >> 6;                      // wave -> n-quarter (64 cols)
    const int quad = lane >> 4, li = lane & 15;
    const int mb = blockIdx.x, ns = blockIdx.y;
    const int ns256 = ns << 8;

    // async stage of one kt B-tile (32 KB = 32 frags x 1KB); wave w stages the
    // 8 fragments it alone consumes (f = w*8..w*8+7). LDS dest is wave-uniform
    // base + lane*16 (global_load_lds semantics); global src is per-lane.
#define STAGEB(nt_, kt_, buf_) do {                                                   \
    _Pragma("unroll")                                                                 \
    for (int i_ = 0; i_ < 8; ++i_) {                                                  \
        int f_ = (w << 3) + i_;                                                       \
        int ntb_ = f_ >> 1, pp_ = f_ & 1;                                             \
        size_t goff_ = ((size_t)((((ns256 + ((nt_) << 4) + ntb_) << 3) + (kt_)) * 2 + pp_) << 10) + (lane << 4); \
        __builtin_amdgcn_global_load_lds(                                             \
            (__attribute__((address_space(1))) unsigned*)(size_t)(fb + goff_),        \
            (__attribute__((address_space(3))) unsigned*)(unsigned)(size_t)(ldsB + ((buf_) << 15) + (f_ << 10)), \
            16, 0, 0);                                                                \
    }                                                                                 \
} while (0)

    STAGEB(0, 0, 0);                          // prologue: B for (nt=0, kt=0)

    // ---- one-time A staging: z[b][c][t0..t0+64) -> hi/lo frag-linear LDS ----
    {
        const float* zb = z + (size_t)(mb >> 4) * C_ * T_ + ((mb & 15) << 6);
#pragma unroll
        for (int p = 0; p < 4; ++p) {
            int c  = p * 64 + (tid >> 2);
            int tq = tid & 3;
            const float* src = zb + (size_t)c * T_ + tq * 16;
            int kt = c >> 5, kg3 = (c >> 3) & 3, j = c & 7;
            unsigned short* d0 = (unsigned short*)(ldsA + (((tq * 8 + kt) * 2 + 0) << 10) + (kg3 << 8) + (j << 1));
            unsigned short* d1 = (unsigned short*)(ldsA + (((tq * 8 + kt) * 2 + 1) << 10) + (kg3 << 8) + (j << 1));
#pragma unroll
            for (int u = 0; u < 4; ++u) {
                float4 v = *(const float4*)(src + u * 4);
                float vv[4] = {v.x, v.y, v.z, v.w};
#pragma unroll
                for (int e = 0; e < 4; ++e) {
                    unsigned short h = f2b(vv[e]);
                    unsigned short l = f2b(vv[e] - b2f(h));
                    int i = u * 4 + e;
                    d0[i * 8] = h;            // i*16 bytes
                    d1[i * 8] = l;
                }
            }
        }
    }
    __syncthreads();                          // A visible + prologue B landed

    float szr[16];
#pragma unroll
    for (int mt = 0; mt < 4; ++mt)
#pragma unroll
        for (int r = 0; r < 4; ++r)
            szr[mt * 4 + r] = sz[(mb << 6) + (mt << 4) + (quad << 2) + r];

    ull key[16];
#pragma unroll
    for (int s = 0; s < 16; ++s) key[s] = ~0ULL;

    for (int nt = 0; nt < 16; ++nt) {
        f32x4 acc[4][4];
#pragma unroll
        for (int i = 0; i < 4; ++i)
#pragma unroll
            for (int j = 0; j < 4; ++j) acc[i][j] = (f32x4){0.f, 0.f, 0.f, 0.f};

#pragma unroll
        for (int kt = 0; kt < 8; ++kt) {
            // phase parity: buffer (kt&1) holds this kt; stage next into the other
            if (kt < 7)       STAGEB(nt, kt + 1, (kt + 1) & 1);
            else if (nt < 15) STAGEB(nt + 1, 0, 0);

            const char* bB = ldsB + ((kt & 1) << 15);
            bf16x8 ah[4], al[4];
#pragma unroll
            for (int mt = 0; mt < 4; ++mt) {
                ah[mt] = *(const bf16x8*)(ldsA + ((((mt << 3) + kt) * 2 + 0) << 10) + (lane << 4));
                al[mt] = *(const bf16x8*)(ldsA + ((((mt << 3) + kt) * 2 + 1) << 10) + (lane << 4));
            }
#pragma unroll
            for (int nt4 = 0; nt4 < 4; ++nt4) {
                const char* bp = bB + ((((w << 2) + nt4) * 2) << 10) + (lane << 4);
                bf16x8 bh = *(const bf16x8*)(bp);
                bf16x8 bl = *(const bf16x8*)(bp + 1024);
#pragma unroll
                for (int mt = 0; mt < 4; ++mt) {
                    f32x4 c = acc[mt][nt4];
                    c = __builtin_amdgcn_mfma_f32_16x16x32_bf16(ah[mt], bh, c, 0, 0, 0);
                    c = __builtin_amdgcn_mfma_f32_16x16x32_bf16(ah[mt], bl, c, 0, 0, 0);
                    c = __builtin_amdgcn_mfma_f32_16x16x32_bf16(al[mt], bh, c, 0, 0, 0);
                    acc[mt][nt4] = c;
                }
            }

            if (kt == 7) {
                // epilogue: quantized ref-formula score -> packed u64 running min
                float sev[4];
#pragma unroll
                for (int nt4 = 0; nt4 < 4; ++nt4)
                    sev[nt4] = se[(ns << 12) + (nt << 8) + (((w << 2) + nt4) << 4) + li];
#pragma unroll
                for (int mt = 0; mt < 4; ++mt)
#pragma unroll
                    for (int r = 0; r < 4; ++r) {
                        int sl = (mt << 2) + r;
                        ull best = key[sl];
#pragma unroll
                        for (int nt4 = 0; nt4 < 4; ++nt4) {
                            int ncol = (ns << 12) + (nt << 8) + (((w << 2) + nt4) << 4) + li;
                            float s = fmaf(-2.f, acc[mt][nt4][r], __fadd_rn(szr[sl], sev[nt4]));
                            ull k = ((ull)__float_as_uint(s) << 32) | (unsigned)ncol;
                            if (k < best) best = k;
                        }
                        key[sl] = best;
                    }
                if (nt & 1) {                 // flush superchunk (2 nt = 128 cols/wave)
#pragma unroll
                    for (int sl = 0; sl < 16; ++sl) {
                        ull kk = key[sl];
#pragma unroll
                        for (int off = 1; off <= 8; off <<= 1) {
                            ull o = __shfl_xor(kk, off, 64);
                            if (o < kk) kk = o;
                        }
                        if (li == 0) {
                            int row = (mb << 6) + ((sl >> 2) << 4) + (quad << 2) + (sl & 3);
                            minima[(size_t)row * 64 + (ns << 5) + ((nt >> 1) << 2) + w] = kk;
                        }
                        key[sl] = ~0ULL;
                    }
                }
            }
            __syncthreads();                  // drain my loads; everyone done reading
        }
    }
#undef STAGEB
}

// ---------------- pass2: top-4 of 64 cells + fp64 fixup + idx out ----------------
// grid 1024, block 256; block owns 16 consecutive rows (z tile staged in LDS).
__global__ __launch_bounds__(256) void vq_pick2(
        const float* __restrict__ z, const float* __restrict__ emb,
        const float* __restrict__ ws, const ull* __restrict__ minima,
        float* __restrict__ out) {
    __shared__ float Lz[256 * 17];            // [c][t0..15], padded
    const float* sz = ws + WS_SZ;
    const float* se = ws + WS_SE;
    const int tid = threadIdx.x;
    const int w = tid >> 6, lane = tid & 63, li = lane & 15;
    const int m0 = blockIdx.x * 16;
    const int b = m0 >> 10, t0 = m0 & (T_ - 1);

    {   // stage z tile: 16 t x 256 c
        const float* src = z + (size_t)b * C_ * T_ + (size_t)tid * T_ + t0;
#pragma unroll
        for (int u = 0; u < 4; ++u) {
            float4 v = *(const float4*)(src + u * 4);
            Lz[tid * 17 + u * 4 + 0] = v.x;
            Lz[tid * 17 + u * 4 + 1] = v.y;
            Lz[tid * 17 + u * 4 + 2] = v.z;
            Lz[tid * 17 + u * 4 + 3] = v.w;
        }
    }
    __syncthreads();

    for (int rr = 0; rr < 4; ++rr) {
        const int tloc = w * 4 + rr;
        const int m = m0 + tloc;
        // top-4 of the 64 jittered cell-minima
        ull kmin = minima[(size_t)m * 64 + lane];
        int cand[4];
#pragma unroll
        for (int rep = 0; rep < 4; ++rep) {
            ull bf = kmin;
#pragma unroll
            for (int off = 1; off <= 32; off <<= 1) {
                ull o = __shfl_xor(bf, off, 64);
                if (o < bf) bf = o;
            }
            int ix = (int)(unsigned)(bf & 0xFFFFFFFFull);
            cand[rep] = ix < 0 ? 0 : (ix > N_ - 1 ? N_ - 1 : ix);
            if (kmin == bf) kmin = ~0ULL;
        }
        // fp64 dots: 4 groups of 16 lanes, one candidate each
        const int cn = cand[lane >> 4];
        const float* ep = emb + (size_t)cn * C_;
        double sum = 0.0;
#pragma unroll
        for (int cc = 0; cc < 16; ++cc) {
            int c = cc * 16 + li;
            sum = fma((double)Lz[c * 17 + tloc], (double)ep[c], sum);
        }
#pragma unroll
        for (int off = 1; off <= 8; off <<= 1)
            sum += __shfl_xor(sum, off, 64);
        double s0 = __shfl(sum, 0, 64), s1 = __shfl(sum, 16, 64);
        double s2 = __shfl(sum, 32, 64), s3 = __shfl(sum, 48, 64);
        if (lane == 0) {
            float szm = sz[m];
            float d0 = fmaf(-2.f, (float)s0, __fadd_rn(szm, se[cand[0]]));
            float d1 = fmaf(-2.f, (float)s1, __fadd_rn(szm, se[cand[1]]));
            float d2 = fmaf(-2.f, (float)s2, __fadd_rn(szm, se[cand[2]]));
            float d3 = fmaf(-2.f, (float)s3, __fadd_rn(szm, se[cand[3]]));
            float bd = d0; int bi = cand[0];
            if (d1 < bd || (d1 == bd && cand[1] < bi)) { bd = d1; bi = cand[1]; }
            if (d2 < bd || (d2 == bd && cand[2] < bi)) { bd = d2; bi = cand[2]; }
            if (d3 < bd || (d3 == bd && cand[3] < bi)) { bd = d3; bi = cand[3]; }
            out[OUT_IDX + m] = (float)bi;
        }
    }
}

// ---------------- fallback round-5 pass1/pass2 (known-PASS) ----------------
__global__ __launch_bounds__(256) void vq_pass1_fp32(
        const float* __restrict__ z,
        const float* __restrict__ emb,
        float* __restrict__ ws) {
    __shared__ float As[32][68];
    __shared__ float Bs[32][68];
    const float* s_z = ws + WS_SZ;
    const float* s_e = ws + WS_SE;
    int* i1ws = (int*)ws + O_I1;
    int* i2ws = (int*)ws + O_I2;
    const int tid = threadIdx.x;
    const int mt  = blockIdx.x;
    const int tx  = tid & 15, ty = tid >> 4;
    const int b   = mt >> 4;
    const int t0  = (mt << 6) & (T_ - 1);
    const float* zbase = z + (size_t)b * C_ * T_ + t0;
    const int a_k = tid >> 4;
    const int a_m = (tid & 15) << 2;
    const int b_j = tid >> 2;
    const int b_q = (tid & 3) << 3;
    const float4 sz4 = *(const float4*)(s_z + mt * 64 + (ty << 2));
    const float szv[4] = {sz4.x, sz4.y, sz4.z, sz4.w};
    float v1[4], v2[4];
    int   i1[4], i2[4];
#pragma unroll
    for (int i = 0; i < 4; ++i) {
        v1[i] = INFINITY; v2[i] = INFINITY;
        i1[i] = 0x7FFFFFFF; i2[i] = 0x7FFFFFFF;
    }
    for (int nt = 0; nt < N_ / 64; ++nt) {
        const int n0 = nt * 64;
        float acc[4][4];
#pragma unroll
        for (int i = 0; i < 4; ++i)
#pragma unroll
            for (int j = 0; j < 4; ++j) acc[i][j] = 0.f;
        for (int kt = 0; kt < C_; kt += 32) {
            __syncthreads();
#pragma unroll
            for (int p = 0; p < 2; ++p) {
                int k = a_k + p * 16;
                float4 af = *(const float4*)(zbase + (size_t)(kt + k) * T_ + a_m);
                *(float4*)&As[k][a_m] = af;
            }
            {
                const float* ep = emb + (size_t)(n0 + b_j) * C_ + kt + b_q;
                float4 e0 = ((const float4*)ep)[0];
                float4 e1 = ((const float4*)ep)[1];
                Bs[b_q + 0][b_j] = e0.x; Bs[b_q + 1][b_j] = e0.y;
                Bs[b_q + 2][b_j] = e0.z; Bs[b_q + 3][b_j] = e0.w;
                Bs[b_q + 4][b_j] = e1.x; Bs[b_q + 5][b_j] = e1.y;
                Bs[b_q + 6][b_j] = e1.z; Bs[b_q + 7][b_j] = e1.w;
            }
            __syncthreads();
#pragma unroll
            for (int k = 0; k < 32; ++k) {
                const float4 a  = *(const float4*)&As[k][ty << 2];
                const float4 bv = *(const float4*)&Bs[k][tx << 2];
                acc[0][0] = fmaf(a.x, bv.x, acc[0][0]);
                acc[0][1] = fmaf(a.x, bv.y, acc[0][1]);
                acc[0][2] = fmaf(a.x, bv.z, acc[0][2]);
                acc[0][3] = fmaf(a.x, bv.w, acc[0][3]);
                acc[1][0] = fmaf(a.y, bv.x, acc[1][0]);
                acc[1][1] = fmaf(a.y, bv.y, acc[1][1]);
                acc[1][2] = fmaf(a.y, bv.z, acc[1][2]);
                acc[1][3] = fmaf(a.y, bv.w, acc[1][3]);
                acc[2][0] = fmaf(a.z, bv.x, acc[2][0]);
                acc[2][1] = fmaf(a.z, bv.y, acc[2][1]);
                acc[2][2] = fmaf(a.z, bv.z, acc[2][2]);
                acc[2][3] = fmaf(a.z, bv.w, acc[2][3]);
                acc[3][0] = fmaf(a.w, bv.x, acc[3][0]);
                acc[3][1] = fmaf(a.w, bv.y, acc[3][1]);
                acc[3][2] = fmaf(a.w, bv.z, acc[3][2]);
                acc[3][3] = fmaf(a.w, bv.w, acc[3][3]);
            }
        }
        const float4 se4 = *(const float4*)(s_e + n0 + (tx << 2));
        const float sev[4] = {se4.x, se4.y, se4.z, se4.w};
#pragma unroll
        for (int j = 0; j < 4; ++j) {
            const int n = n0 + (tx << 2) + j;
#pragma unroll
            for (int i = 0; i < 4; ++i) {
                float A = __fadd_rn(szv[i], sev[j]);
                float s = fmaf(-2.f, acc[i][j], A);
                if (s < v1[i]) { v2[i] = v1[i]; i2[i] = i1[i]; v1[i] = s; i1[i] = n; }
                else if (s < v2[i]) { v2[i] = s; i2[i] = n; }
            }
        }
    }
#pragma unroll
    for (int i = 0; i < 4; ++i) {
        float a1 = v1[i], a2 = v2[i];
        int   y1 = i1[i], y2 = i2[i];
#pragma unroll
        for (int off = 8; off >= 1; off >>= 1) {
            float o1 = __shfl_xor(a1, off, 64); int p1 = __shfl_xor(y1, off, 64);
            float o2 = __shfl_xor(a2, off, 64); int p2 = __shfl_xor(y2, off, 64);
            bool alt = (o1 < a1) || (o1 == a1 && p1 < y1);
            float w1 = alt ? o1 : a1; int q1 = alt ? p1 : y1;
            float lv = alt ? a1 : o1; int lq = alt ? y1 : p1;
            float wv = alt ? o2 : a2; int wq = alt ? p2 : y2;
            bool sb = (lv < wv) || (lv == wv && lq < wq);
            a2 = sb ? lv : wv; y2 = sb ? lq : wq;
            a1 = w1; y1 = q1;
        }
        if (tx == 0) {
            int m = mt * 64 + (ty << 2) + i;
            i1ws[m] = y1;
            i2ws[m] = y2;
        }
    }
}

__global__ __launch_bounds__(256) void vq_pass2_fp32(
        const float* __restrict__ z,
        const float* __restrict__ emb,
        float* __restrict__ ws,
        float* __restrict__ out) {
    const float* s_z = ws + WS_SZ;
    const float* s_e = ws + WS_SE;
    const int* i1ws = (const int*)ws + O_I1;
    const int* i2ws = (const int*)ws + O_I2;
    const int tid  = threadIdx.x;
    const int wave = tid >> 6, lane = tid & 63;
    const int half = lane >> 5;
    const int c0   = (lane & 31) << 3;
    const int rowbase = (blockIdx.x * 4 + wave) * 64;
    for (int r = 0; r < 64; ++r) {
        const int m = rowbase + r;
        int c1 = i1ws[m], c2 = i2ws[m];
        c1 = c1 < 0 ? 0 : (c1 > N_ - 1 ? N_ - 1 : c1);
        c2 = c2 < 0 ? 0 : (c2 > N_ - 1 ? N_ - 1 : c2);
        const int b = m >> 10, t = m & (T_ - 1);
        const float* zp = z + (size_t)b * C_ * T_ + t;
        const int cand = half ? c2 : c1;
        const float* ep = emb + (size_t)cand * C_;
        double sum = 0.0;
#pragma unroll
        for (int c = 0; c < 8; ++c)
            sum = fma((double)zp[(size_t)(c0 + c) * T_], (double)ep[c0 + c], sum);
#pragma unroll
        for (int off = 1; off <= 16; off <<= 1)
            sum += __shfl_xor(sum, off, 64);
        double s1 = __shfl(sum, 0, 64);
        double s2 = __shfl(sum, 32, 64);
        if (lane == 0) {
            float p1 = (float)s1, p2 = (float)s2;
            float d1 = fmaf(-2.f, p1, __fadd_rn(s_z[m], s_e[c1]));
            float d2 = fmaf(-2.f, p2, __fadd_rn(s_z[m], s_e[c2]));
            int win = ((d2 < d1) || (d2 == d1 && c2 < c1)) ? c2 : c1;
            out[OUT_IDX + m] = (float)win;
        }
    }
}

// ---------------- gather z_q (transposed) + loss partial; idx from out ----------------
__global__ __launch_bounds__(256) void vq_gather(
        const float* __restrict__ z,
        const float* __restrict__ emb,
        float* __restrict__ partial,
        float* __restrict__ out) {
    __shared__ float Ls[64][129];
    __shared__ int   idxs[64];
    __shared__ float wred[4];
    const int tid = threadIdx.x;
    const int mg  = blockIdx.x;
    const int m0  = mg << 6;
    const int b   = m0 >> 10;
    const int t0  = m0 & (T_ - 1);
    if (tid < 64) {
        int ix = (int)out[OUT_IDX + m0 + tid];
        idxs[tid] = ix < 0 ? 0 : (ix > N_ - 1 ? N_ - 1 : ix);
    }
    __syncthreads();
    float lsum = 0.f;
    const int w = tid >> 6, l = tid & 63;
    const int tt2 = tid & 63, c0 = tid >> 6;
    const size_t base = (size_t)b * (C_ * T_) + t0 + tt2;
#pragma unroll
    for (int ch = 0; ch < 2; ++ch) {
        __syncthreads();
#pragma unroll
        for (int it = 0; it < 8; ++it) {
            int tt = it * 8 + w * 2 + (l >> 5);
            int cq = l & 31;
            int row = idxs[tt];
            float4 ev = *(const float4*)(emb + (size_t)row * C_ + ch * 128 + (cq << 2));
            Ls[tt][(cq << 2) + 0] = ev.x;
            Ls[tt][(cq << 2) + 1] = ev.y;
            Ls[tt][(cq << 2) + 2] = ev.z;
            Ls[tt][(cq << 2) + 3] = ev.w;
        }
        __syncthreads();
#pragma unroll
        for (int st = 0; st < 32; ++st) {
            int c_l = (st << 2) + c0;
            int c   = (ch << 7) + c_l;
            float v = Ls[tt2][c_l];
            size_t off = base + (size_t)c * T_;
            out[OUT_ZQ + off] = v;
            float d = v - z[off];
            lsum = fmaf(d, d, lsum);
        }
    }
#pragma unroll
    for (int off = 32; off >= 1; off >>= 1) lsum += __shfl_xor(lsum, off, 64);
    if (l == 0) wred[w] = lsum;
    __syncthreads();
    if (tid == 0) partial[mg] = wred[0] + wred[1] + wred[2] + wred[3];
}

__global__ __launch_bounds__(256) void vq_loss(const float* __restrict__ partial,
                                               float* __restrict__ out) {
    __shared__ float wred[4];
    const int tid = threadIdx.x;
    float v = partial[tid];
#pragma unroll
    for (int off = 32; off >= 1; off >>= 1) v += __shfl_xor(v, off, 64);
    if ((tid & 63) == 0) wred[tid >> 6] = v;
    __syncthreads();
    if (tid == 0)
        out[OUT_LOSS] = (wred[0] + wred[1] + wred[2] + wred[3]) * (1.25f / 4194304.f);
}

extern "C" void kernel_launch(void* const* d_in, const int* in_sizes, int n_in,
                              void* d_out, int out_size, void* d_ws, size_t ws_size,
                              hipStream_t stream) {
    const float* z   = (const float*)d_in[0];
    const float* emb = (const float*)d_in[1];
    float* out = (float*)d_out;
    float* ws  = (float*)d_ws;

    vq_sums<<<dim3((M_ + N_) / 256), dim3(256), 0, stream>>>(z, emb, ws);

    if (ws_size >= WS_NEED) {   // fast MFMA path
        char* fb = (char*)d_ws + FB_OFF;
        ull* minima = (ull*)((char*)d_ws + MIN_OFF);
        vq_prep_b<<<dim3(1024), dim3(256), 0, stream>>>(emb, fb);
        vq_mfma4<<<dim3(256, 2), dim3(256), 0, stream>>>(z, fb, ws + WS_SZ, ws + WS_SE, minima);
        vq_pick2<<<dim3(1024), dim3(256), 0, stream>>>(z, emb, ws, minima, out);
        vq_gather<<<dim3(M_ / 64), dim3(256), 0, stream>>>(z, emb, ws + WS_PART, out);
        vq_loss<<<dim3(1), dim3(256), 0, stream>>>(ws + WS_PART, out);
    } else {                    // round-5 fallback (known-PASS)
        vq_pass1_fp32<<<dim3(M_ / 64), dim3(256), 0, stream>>>(z, emb, ws);
        vq_pass2_fp32<<<dim3(64), dim3(256), 0, stream>>>(z, emb, ws, out);
        vq_gather<<<dim3(M_ / 64), dim3(256), 0, stream>>>(z, emb, ws + O_PART, out);
        vq_loss<<<dim3(1), dim3(256), 0, stream>>>(ws + O_PART, out);
    }
}

// Round 3
// 349.019 us; speedup vs baseline: 1.4749x; 1.0163x over previous
//
#include <hip/hip_runtime.h>

// VectorQuantizer: z [16,256,1024] fp32, emb [8192,256] fp32.
// out (FP32): [ z_q 4194304 | loss 1 | idx 16384 ]
// Ref emulation: d = fl(fl(s_z+s_e) - 2p), argmin w/ lowest-index ties.
// Fast path: split-bf16 (hi/lo) MFMA GEMM. A (64m x 256k hi/lo) cached in
// REGISTERS per wave (loaded once from LDS); B streamed through wave-PRIVATE
// double-buffered LDS via async global_load_lds with counted vmcnt(8) waits.
// ZERO barriers in the whole nt/kt loop -> no lockstep, LDS traffic = B only.
// Block = 64m x 8192n (grid 256, 1 block/CU); wave = 64m x 64n per nt step;
// 2-nt pairing keeps each wave in one 128-col cell -> validated 64-cell
// minima + top-4-of-64 fp64 fixup. Per-dot MFMA op sequence identical.

#define C_    256
#define T_    1024
#define M_    16384
#define N_    8192

#define OUT_ZQ   0
#define OUT_LOSS 4194304
#define OUT_IDX  4194305

// ---- ws layout, fast path ----
#define WS_SZ    0           // s_z [16384] float
#define WS_SE    16384       // s_e [8192] float
#define WS_PART  24576       // loss partials [256] float   (ends byte 99328)
#define MIN_OFF  131072u     // bytes: u64 minima [16384 rows][64 cells] = 8 MB
#define FB_OFF   8519680u    // bytes: frag-linear emb hi/lo, 8 MB
#define WS_NEED  16908288u   // bytes (< 25.69 MB proven available)
// ---- ws layout, fallback (round-5, known-PASS) ----
#define O_I1     24576
#define O_I2     40960
#define O_PART   73728

typedef __attribute__((ext_vector_type(8))) short bf16x8;
typedef __attribute__((ext_vector_type(4))) float f32x4;
typedef unsigned long long ull;

__device__ __forceinline__ unsigned short f2b(float f) {
    unsigned u = __float_as_uint(f);
    return (unsigned short)((u + 0x7FFFu + ((u >> 16) & 1u)) >> 16);   // RTNE
}
__device__ __forceinline__ float b2f(unsigned short u) {
    return __uint_as_float(((unsigned)u) << 16);
}

// ---------------- s_z / s_e: numpy pairwise_sum replication ----------------
__global__ __launch_bounds__(256) void vq_sums(const float* __restrict__ z,
                                               const float* __restrict__ emb,
                                               float* __restrict__ ws) {
    int gid = blockIdx.x * 256 + threadIdx.x;
    if (gid < M_) {
        int b = gid >> 10, t = gid & (T_ - 1);
        const float* zp = z + (size_t)b * C_ * T_ + t;
        float blk[2];
#pragma unroll
        for (int h = 0; h < 2; ++h) {
            float r[8];
#pragma unroll
            for (int j = 0; j < 8; ++j) {
                float v = zp[(size_t)(h * 128 + j) * T_];
                r[j] = __fmul_rn(v, v);
            }
            for (int i = 8; i < 128; i += 8)
#pragma unroll
                for (int j = 0; j < 8; ++j) {
                    float v = zp[(size_t)(h * 128 + i + j) * T_];
                    r[j] = __fadd_rn(r[j], __fmul_rn(v, v));
                }
            blk[h] = __fadd_rn(__fadd_rn(__fadd_rn(r[0], r[1]), __fadd_rn(r[2], r[3])),
                               __fadd_rn(__fadd_rn(r[4], r[5]), __fadd_rn(r[6], r[7])));
        }
        ws[WS_SZ + gid] = __fadd_rn(blk[0], blk[1]);
    } else if (gid < M_ + N_) {
        int n = gid - M_;
        const float* ep = emb + (size_t)n * C_;
        float blk[2];
#pragma unroll
        for (int h = 0; h < 2; ++h) {
            float r[8];
#pragma unroll
            for (int j = 0; j < 8; ++j) {
                float v = ep[h * 128 + j];
                r[j] = __fmul_rn(v, v);
            }
            for (int i = 8; i < 128; i += 8)
#pragma unroll
                for (int j = 0; j < 8; ++j) {
                    float v = ep[h * 128 + i + j];
                    r[j] = __fadd_rn(r[j], __fmul_rn(v, v));
                }
            blk[h] = __fadd_rn(__fadd_rn(__fadd_rn(r[0], r[1]), __fadd_rn(r[2], r[3])),
                               __fadd_rn(__fadd_rn(r[4], r[5]), __fadd_rn(r[6], r[7])));
        }
        ws[WS_SE + n] = __fadd_rn(blk[0], blk[1]);
    }
}

// ---------------- prep: emb -> frag-linear bf16 hi/lo (fb) ----------------
__global__ __launch_bounds__(256) void vq_prep_b(const float* __restrict__ emb,
                                                 char* __restrict__ fb) {
    int gid = blockIdx.x * 256 + threadIdx.x;     // 262144
    int n = gid >> 5, kg = gid & 31;
    const float* ep = emb + (size_t)n * C_ + kg * 8;
    unsigned hi[8], lo[8];
#pragma unroll
    for (int j = 0; j < 8; ++j) {
        float v = ep[j];
        unsigned short h = f2b(v);
        hi[j] = h;
        lo[j] = f2b(v - b2f(h));
    }
    int nt = n >> 4, kt = kg >> 2, lane = (kg & 3) * 16 + (n & 15);
    size_t base = ((size_t)((nt * 8 + kt) * 2) << 10) + (lane << 4);
    uint4 hv = {hi[0] | (hi[1] << 16), hi[2] | (hi[3] << 16), hi[4] | (hi[5] << 16), hi[6] | (hi[7] << 16)};
    uint4 lv = {lo[0] | (lo[1] << 16), lo[2] | (lo[3] << 16), lo[4] | (lo[5] << 16), lo[6] | (lo[7] << 16)};
    *(uint4*)(fb + base) = hv;
    *(uint4*)(fb + base + 1024) = lv;
}

// ---------------- pass1: MFMA GEMM, A in registers, B wave-private async LDS ----------
// grid 256 (one 64m block per CU), block 256 (4 waves, each 64m x 64n per nt step,
// sweeping all 8192 cols in 32 nt steps; 2-nt pairs = one 128-col cell per wave).
__global__ __launch_bounds__(256, 1) void vq_mfma5(
        const float* __restrict__ z, const char* __restrict__ fb,
        const float* __restrict__ sz, const float* __restrict__ se,
        ull* __restrict__ minima) {
    __shared__ __align__(16) char ldsA[65536];   // 64m x 256k hi/lo, frag-linear (staging)
    __shared__ __align__(16) char ldsB[65536];   // 4 waves x 2 bufs x 8 KB, wave-private

    const int tid = threadIdx.x;
    const int lane = tid & 63;
    const int w = tid >> 6;
    const int quad = lane >> 4, li = lane & 15;
    const int mb = blockIdx.x;

    char* wbuf = ldsB + (w << 14);               // this wave's private 16 KB

    // wave's 4 ntiles for step nt: pairs of nt share one 128-col cell
#define NTILE0(nt_) ((((nt_) >> 1) << 5) + (w << 3) + (((nt_) & 1) << 2))

    // stage this wave's 8 B fragments (8 KB) for (ntile0, kt) into buf.
    // LDS dest = wave-uniform base (+ lane*16 by HW); global src per-lane.
#define STAGEB(ntile0_, kt_, buf_) do {                                               \
    _Pragma("unroll")                                                                 \
    for (int f_ = 0; f_ < 8; ++f_) {                                                  \
        int ntb_ = f_ >> 1, pp_ = f_ & 1;                                             \
        size_t goff_ = ((size_t)((((ntile0_) + ntb_) * 8 + (kt_)) * 2 + pp_) << 10) + (lane << 4); \
        __builtin_amdgcn_global_load_lds(                                             \
            (__attribute__((address_space(1))) unsigned*)(size_t)(fb + goff_),        \
            (__attribute__((address_space(3))) unsigned*)(unsigned)(size_t)(wbuf + ((buf_) << 13) + (f_ << 10)), \
            16, 0, 0);                                                                \
    }                                                                                 \
} while (0)

    STAGEB(NTILE0(0), 0, 0);                  // prologue: B for (nt=0, kt=0)

    // ---- one-time A staging: z[b][c][t0..t0+64) -> hi/lo frag-linear LDS ----
    {
        const float* zb = z + (size_t)(mb >> 4) * C_ * T_ + ((mb & 15) << 6);
#pragma unroll
        for (int p = 0; p < 4; ++p) {
            int c  = p * 64 + (tid >> 2);
            int tq = tid & 3;
            const float* src = zb + (size_t)c * T_ + tq * 16;
            int kt = c >> 5, kg3 = (c >> 3) & 3, j = c & 7;
            unsigned short* d0 = (unsigned short*)(ldsA + (((tq * 8 + kt) * 2 + 0) << 10) + (kg3 << 8) + (j << 1));
            unsigned short* d1 = (unsigned short*)(ldsA + (((tq * 8 + kt) * 2 + 1) << 10) + (kg3 << 8) + (j << 1));
#pragma unroll
            for (int u = 0; u < 4; ++u) {
                float4 v = *(const float4*)(src + u * 4);
                float vv[4] = {v.x, v.y, v.z, v.w};
#pragma unroll
                for (int e = 0; e < 4; ++e) {
                    unsigned short h = f2b(vv[e]);
                    unsigned short l = f2b(vv[e] - b2f(h));
                    int i = u * 4 + e;
                    d0[i * 8] = h;            // i*16 bytes
                    d1[i * 8] = l;
                }
            }
        }
    }
    __syncthreads();                          // ONLY barrier: A staged, prologue B issued

    // ---- A -> registers: all 64 fragments (256 VGPRs), read once ----
    bf16x8 Ah[4][8], Al[4][8];
#pragma unroll
    for (int mt = 0; mt < 4; ++mt)
#pragma unroll
        for (int kt = 0; kt < 8; ++kt) {
            Ah[mt][kt] = *(const bf16x8*)(ldsA + ((((mt << 3) + kt) * 2 + 0) << 10) + (lane << 4));
            Al[mt][kt] = *(const bf16x8*)(ldsA + ((((mt << 3) + kt) * 2 + 1) << 10) + (lane << 4));
        }

    float szr[16];
#pragma unroll
    for (int mt = 0; mt < 4; ++mt)
#pragma unroll
        for (int r = 0; r < 4; ++r)
            szr[mt * 4 + r] = sz[(mb << 6) + (mt << 4) + (quad << 2) + r];

    ull key[16];
#pragma unroll
    for (int s = 0; s < 16; ++s) key[s] = ~0ULL;

    for (int nt = 0; nt < 32; ++nt) {
        const int ntile0 = NTILE0(nt);
        f32x4 acc[4][4];
#pragma unroll
        for (int i = 0; i < 4; ++i)
#pragma unroll
            for (int j = 0; j < 4; ++j) acc[i][j] = (f32x4){0.f, 0.f, 0.f, 0.f};

#pragma unroll
        for (int kt = 0; kt < 8; ++kt) {
            const int cb = kt & 1;            // buffer holding this kt (static)
            // stage next phase into the other buffer (none at the very end)
            if (kt < 7)       STAGEB(ntile0, kt + 1, cb ^ 1);
            else if (nt < 31) STAGEB(NTILE0(nt + 1), 0, cb ^ 1);
            // counted wait: oldest 8 (this kt's loads, issued last phase) landed
            if (kt == 7 && nt == 31) {
                asm volatile("s_waitcnt vmcnt(0)" ::: "memory");
            } else {
                asm volatile("s_waitcnt vmcnt(8)" ::: "memory");
            }
            __builtin_amdgcn_sched_barrier(0);
#pragma unroll
            for (int nt4 = 0; nt4 < 4; ++nt4) {
                const char* bp = wbuf + (cb << 13) + ((nt4 * 2) << 10) + (lane << 4);
                bf16x8 bh = *(const bf16x8*)(bp);
                bf16x8 bl = *(const bf16x8*)(bp + 1024);
#pragma unroll
                for (int mt = 0; mt < 4; ++mt) {
                    f32x4 c = acc[mt][nt4];
                    c = __builtin_amdgcn_mfma_f32_16x16x32_bf16(Ah[mt][kt], bh, c, 0, 0, 0);
                    c = __builtin_amdgcn_mfma_f32_16x16x32_bf16(Ah[mt][kt], bl, c, 0, 0, 0);
                    c = __builtin_amdgcn_mfma_f32_16x16x32_bf16(Al[mt][kt], bh, c, 0, 0, 0);
                    acc[mt][nt4] = c;
                }
            }
            __builtin_amdgcn_sched_barrier(0);  // fence: next STAGE can't hoist over reads
        }

        // epilogue: quantized ref-formula score -> packed u64 running min
        float sev[4];
#pragma unroll
        for (int nt4 = 0; nt4 < 4; ++nt4)
            sev[nt4] = se[((ntile0 + nt4) << 4) + li];
#pragma unroll
        for (int mt = 0; mt < 4; ++mt)
#pragma unroll
            for (int r = 0; r < 4; ++r) {
                int sl = (mt << 2) + r;
                ull best = key[sl];
#pragma unroll
                for (int nt4 = 0; nt4 < 4; ++nt4) {
                    int ncol = ((ntile0 + nt4) << 4) + li;
                    float s = fmaf(-2.f, acc[mt][nt4][r], __fadd_rn(szr[sl], sev[nt4]));
                    ull k = ((ull)__float_as_uint(s) << 32) | (unsigned)ncol;
                    if (k < best) best = k;
                }
                key[sl] = best;
            }
        if (nt & 1) {                         // flush cell (2 nt = 128 cols/wave)
#pragma unroll
            for (int sl = 0; sl < 16; ++sl) {
                ull kk = key[sl];
#pragma unroll
                for (int off = 1; off <= 8; off <<= 1) {
                    ull o = __shfl_xor(kk, off, 64);
                    if (o < kk) kk = o;
                }
                if (li == 0) {
                    int row = (mb << 6) + ((sl >> 2) << 4) + (quad << 2) + (sl & 3);
                    minima[(size_t)row * 64 + (((nt >> 1) << 2) + w)] = kk;
                }
                key[sl] = ~0ULL;
            }
        }
    }
#undef STAGEB
#undef NTILE0
}

// ---------------- pass2: top-4 of 64 cells + fp64 fixup + idx out ----------------
// grid 1024, block 256; block owns 16 consecutive rows (z tile staged in LDS).
__global__ __launch_bounds__(256) void vq_pick2(
        const float* __restrict__ z, const float* __restrict__ emb,
        const float* __restrict__ ws, const ull* __restrict__ minima,
        float* __restrict__ out) {
    __shared__ float Lz[256 * 17];            // [c][t0..15], padded
    const float* sz = ws + WS_SZ;
    const float* se = ws + WS_SE;
    const int tid = threadIdx.x;
    const int w = tid >> 6, lane = tid & 63, li = lane & 15;
    const int m0 = blockIdx.x * 16;
    const int b = m0 >> 10, t0 = m0 & (T_ - 1);

    {   // stage z tile: 16 t x 256 c
        const float* src = z + (size_t)b * C_ * T_ + (size_t)tid * T_ + t0;
#pragma unroll
        for (int u = 0; u < 4; ++u) {
            float4 v = *(const float4*)(src + u * 4);
            Lz[tid * 17 + u * 4 + 0] = v.x;
            Lz[tid * 17 + u * 4 + 1] = v.y;
            Lz[tid * 17 + u * 4 + 2] = v.z;
            Lz[tid * 17 + u * 4 + 3] = v.w;
        }
    }
    __syncthreads();

    for (int rr = 0; rr < 4; ++rr) {
        const int tloc = w * 4 + rr;
        const int m = m0 + tloc;
        // top-4 of the 64 jittered cell-minima
        ull kmin = minima[(size_t)m * 64 + lane];
        int cand[4];
#pragma unroll
        for (int rep = 0; rep < 4; ++rep) {
            ull bf = kmin;
#pragma unroll
            for (int off = 1; off <= 32; off <<= 1) {
                ull o = __shfl_xor(bf, off, 64);
                if (o < bf) bf = o;
            }
            int ix = (int)(unsigned)(bf & 0xFFFFFFFFull);
            cand[rep] = ix < 0 ? 0 : (ix > N_ - 1 ? N_ - 1 : ix);
            if (kmin == bf) kmin = ~0ULL;
        }
        // fp64 dots: 4 groups of 16 lanes, one candidate each
        const int cn = cand[lane >> 4];
        const float* ep = emb + (size_t)cn * C_;
        double sum = 0.0;
#pragma unroll
        for (int cc = 0; cc < 16; ++cc) {
            int c = cc * 16 + li;
            sum = fma((double)Lz[c * 17 + tloc], (double)ep[c], sum);
        }
#pragma unroll
        for (int off = 1; off <= 8; off <<= 1)
            sum += __shfl_xor(sum, off, 64);
        double s0 = __shfl(sum, 0, 64), s1 = __shfl(sum, 16, 64);
        double s2 = __shfl(sum, 32, 64), s3 = __shfl(sum, 48, 64);
        if (lane == 0) {
            float szm = sz[m];
            float d0 = fmaf(-2.f, (float)s0, __fadd_rn(szm, se[cand[0]]));
            float d1 = fmaf(-2.f, (float)s1, __fadd_rn(szm, se[cand[1]]));
            float d2 = fmaf(-2.f, (float)s2, __fadd_rn(szm, se[cand[2]]));
            float d3 = fmaf(-2.f, (float)s3, __fadd_rn(szm, se[cand[3]]));
            float bd = d0; int bi = cand[0];
            if (d1 < bd || (d1 == bd && cand[1] < bi)) { bd = d1; bi = cand[1]; }
            if (d2 < bd || (d2 == bd && cand[2] < bi)) { bd = d2; bi = cand[2]; }
            if (d3 < bd || (d3 == bd && cand[3] < bi)) { bd = d3; bi = cand[3]; }
            out[OUT_IDX + m] = (float)bi;
        }
    }
}

// ---------------- fallback round-5 pass1/pass2 (known-PASS) ----------------
__global__ __launch_bounds__(256) void vq_pass1_fp32(
        const float* __restrict__ z,
        const float* __restrict__ emb,
        float* __restrict__ ws) {
    __shared__ float As[32][68];
    __shared__ float Bs[32][68];
    const float* s_z = ws + WS_SZ;
    const float* s_e = ws + WS_SE;
    int* i1ws = (int*)ws + O_I1;
    int* i2ws = (int*)ws + O_I2;
    const int tid = threadIdx.x;
    const int mt  = blockIdx.x;
    const int tx  = tid & 15, ty = tid >> 4;
    const int b   = mt >> 4;
    const int t0  = (mt << 6) & (T_ - 1);
    const float* zbase = z + (size_t)b * C_ * T_ + t0;
    const int a_k = tid >> 4;
    const int a_m = (tid & 15) << 2;
    const int b_j = tid >> 2;
    const int b_q = (tid & 3) << 3;
    const float4 sz4 = *(const float4*)(s_z + mt * 64 + (ty << 2));
    const float szv[4] = {sz4.x, sz4.y, sz4.z, sz4.w};
    float v1[4], v2[4];
    int   i1[4], i2[4];
#pragma unroll
    for (int i = 0; i < 4; ++i) {
        v1[i] = INFINITY; v2[i] = INFINITY;
        i1[i] = 0x7FFFFFFF; i2[i] = 0x7FFFFFFF;
    }
    for (int nt = 0; nt < N_ / 64; ++nt) {
        const int n0 = nt * 64;
        float acc[4][4];
#pragma unroll
        for (int i = 0; i < 4; ++i)
#pragma unroll
            for (int j = 0; j < 4; ++j) acc[i][j] = 0.f;
        for (int kt = 0; kt < C_; kt += 32) {
            __syncthreads();
#pragma unroll
            for (int p = 0; p < 2; ++p) {
                int k = a_k + p * 16;
                float4 af = *(const float4*)(zbase + (size_t)(kt + k) * T_ + a_m);
                *(float4*)&As[k][a_m] = af;
            }
            {
                const float* ep = emb + (size_t)(n0 + b_j) * C_ + kt + b_q;
                float4 e0 = ((const float4*)ep)[0];
                float4 e1 = ((const float4*)ep)[1];
                Bs[b_q + 0][b_j] = e0.x; Bs[b_q + 1][b_j] = e0.y;
                Bs[b_q + 2][b_j] = e0.z; Bs[b_q + 3][b_j] = e0.w;
                Bs[b_q + 4][b_j] = e1.x; Bs[b_q + 5][b_j] = e1.y;
                Bs[b_q + 6][b_j] = e1.z; Bs[b_q + 7][b_j] = e1.w;
            }
            __syncthreads();
#pragma unroll
            for (int k = 0; k < 32; ++k) {
                const float4 a  = *(const float4*)&As[k][ty << 2];
                const float4 bv = *(const float4*)&Bs[k][tx << 2];
                acc[0][0] = fmaf(a.x, bv.x, acc[0][0]);
                acc[0][1] = fmaf(a.x, bv.y, acc[0][1]);
                acc[0][2] = fmaf(a.x, bv.z, acc[0][2]);
                acc[0][3] = fmaf(a.x, bv.w, acc[0][3]);
                acc[1][0] = fmaf(a.y, bv.x, acc[1][0]);
                acc[1][1] = fmaf(a.y, bv.y, acc[1][1]);
                acc[1][2] = fmaf(a.y, bv.z, acc[1][2]);
                acc[1][3] = fmaf(a.y, bv.w, acc[1][3]);
                acc[2][0] = fmaf(a.z, bv.x, acc[2][0]);
                acc[2][1] = fmaf(a.z, bv.y, acc[2][1]);
                acc[2][2] = fmaf(a.z, bv.z, acc[2][2]);
                acc[2][3] = fmaf(a.z, bv.w, acc[2][3]);
                acc[3][0] = fmaf(a.w, bv.x, acc[3][0]);
                acc[3][1] = fmaf(a.w, bv.y, acc[3][1]);
                acc[3][2] = fmaf(a.w, bv.z, acc[3][2]);
                acc[3][3] = fmaf(a.w, bv.w, acc[3][3]);
            }
        }
        const float4 se4 = *(const float4*)(s_e + n0 + (tx << 2));
        const float sev[4] = {se4.x, se4.y, se4.z, se4.w};
#pragma unroll
        for (int j = 0; j < 4; ++j) {
            const int n = n0 + (tx << 2) + j;
#pragma unroll
            for (int i = 0; i < 4; ++i) {
                float A = __fadd_rn(szv[i], sev[j]);
                float s = fmaf(-2.f, acc[i][j], A);
                if (s < v1[i]) { v2[i] = v1[i]; i2[i] = i1[i]; v1[i] = s; i1[i] = n; }
                else if (s < v2[i]) { v2[i] = s; i2[i] = n; }
            }
        }
    }
#pragma unroll
    for (int i = 0; i < 4; ++i) {
        float a1 = v1[i], a2 = v2[i];
        int   y1 = i1[i], y2 = i2[i];
#pragma unroll
        for (int off = 8; off >= 1; off >>= 1) {
            float o1 = __shfl_xor(a1, off, 64); int p1 = __shfl_xor(y1, off, 64);
            float o2 = __shfl_xor(a2, off, 64); int p2 = __shfl_xor(y2, off, 64);
            bool alt = (o1 < a1) || (o1 == a1 && p1 < y1);
            float w1 = alt ? o1 : a1; int q1 = alt ? p1 : y1;
            float lv = alt ? a1 : o1; int lq = alt ? y1 : p1;
            float wv = alt ? o2 : a2; int wq = alt ? p2 : y2;
            bool sb = (lv < wv) || (lv == wv && lq < wq);
            a2 = sb ? lv : wv; y2 = sb ? lq : wq;
            a1 = w1; y1 = q1;
        }
        if (tx == 0) {
            int m = mt * 64 + (ty << 2) + i;
            i1ws[m] = y1;
            i2ws[m] = y2;
        }
    }
}

__global__ __launch_bounds__(256) void vq_pass2_fp32(
        const float* __restrict__ z,
        const float* __restrict__ emb,
        float* __restrict__ ws,
        float* __restrict__ out) {
    const float* s_z = ws + WS_SZ;
    const float* s_e = ws + WS_SE;
    const int* i1ws = (const int*)ws + O_I1;
    const int* i2ws = (const int*)ws + O_I2;
    const int tid  = threadIdx.x;
    const int wave = tid >> 6, lane = tid & 63;
    const int half = lane >> 5;
    const int c0   = (lane & 31) << 3;
    const int rowbase = (blockIdx.x * 4 + wave) * 64;
    for (int r = 0; r < 64; ++r) {
        const int m = rowbase + r;
        int c1 = i1ws[m], c2 = i2ws[m];
        c1 = c1 < 0 ? 0 : (c1 > N_ - 1 ? N_ - 1 : c1);
        c2 = c2 < 0 ? 0 : (c2 > N_ - 1 ? N_ - 1 : c2);
        const int b = m >> 10, t = m & (T_ - 1);
        const float* zp = z + (size_t)b * C_ * T_ + t;
        const int cand = half ? c2 : c1;
        const float* ep = emb + (size_t)cand * C_;
        double sum = 0.0;
#pragma unroll
        for (int c = 0; c < 8; ++c)
            sum = fma((double)zp[(size_t)(c0 + c) * T_], (double)ep[c0 + c], sum);
#pragma unroll
        for (int off = 1; off <= 16; off <<= 1)
            sum += __shfl_xor(sum, off, 64);
        double s1 = __shfl(sum, 0, 64);
        double s2 = __shfl(sum, 32, 64);
        if (lane == 0) {
            float p1 = (float)s1, p2 = (float)s2;
            float d1 = fmaf(-2.f, p1, __fadd_rn(s_z[m], s_e[c1]));
            float d2 = fmaf(-2.f, p2, __fadd_rn(s_z[m], s_e[c2]));
            int win = ((d2 < d1) || (d2 == d1 && c2 < c1)) ? c2 : c1;
            out[OUT_IDX + m] = (float)win;
        }
    }
}

// ---------------- gather z_q (transposed) + loss partial; idx from out ----------------
__global__ __launch_bounds__(256) void vq_gather(
        const float* __restrict__ z,
        const float* __restrict__ emb,
        float* __restrict__ partial,
        float* __restrict__ out) {
    __shared__ float Ls[64][129];
    __shared__ int   idxs[64];
    __shared__ float wred[4];
    const int tid = threadIdx.x;
    const int mg  = blockIdx.x;
    const int m0  = mg << 6;
    const int b   = m0 >> 10;
    const int t0  = m0 & (T_ - 1);
    if (tid < 64) {
        int ix = (int)out[OUT_IDX + m0 + tid];
        idxs[tid] = ix < 0 ? 0 : (ix > N_ - 1 ? N_ - 1 : ix);
    }
    __syncthreads();
    float lsum = 0.f;
    const int w = tid >> 6, l = tid & 63;
    const int tt2 = tid & 63, c0 = tid >> 6;
    const size_t base = (size_t)b * (C_ * T_) + t0 + tt2;
#pragma unroll
    for (int ch = 0; ch < 2; ++ch) {
        __syncthreads();
#pragma unroll
        for (int it = 0; it < 8; ++it) {
            int tt = it * 8 + w * 2 + (l >> 5);
            int cq = l & 31;
            int row = idxs[tt];
            float4 ev = *(const float4*)(emb + (size_t)row * C_ + ch * 128 + (cq << 2));
            Ls[tt][(cq << 2) + 0] = ev.x;
            Ls[tt][(cq << 2) + 1] = ev.y;
            Ls[tt][(cq << 2) + 2] = ev.z;
            Ls[tt][(cq << 2) + 3] = ev.w;
        }
        __syncthreads();
#pragma unroll
        for (int st = 0; st < 32; ++st) {
            int c_l = (st << 2) + c0;
            int c   = (ch << 7) + c_l;
            float v = Ls[tt2][c_l];
            size_t off = base + (size_t)c * T_;
            out[OUT_ZQ + off] = v;
            float d = v - z[off];
            lsum = fmaf(d, d, lsum);
        }
    }
#pragma unroll
    for (int off = 32; off >= 1; off >>= 1) lsum += __shfl_xor(lsum, off, 64);
    if (l == 0) wred[w] = lsum;
    __syncthreads();
    if (tid == 0) partial[mg] = wred[0] + wred[1] + wred[2] + wred[3];
}

__global__ __launch_bounds__(256) void vq_loss(const float* __restrict__ partial,
                                               float* __restrict__ out) {
    __shared__ float wred[4];
    const int tid = threadIdx.x;
    float v = partial[tid];
#pragma unroll
    for (int off = 32; off >= 1; off >>= 1) v += __shfl_xor(v, off, 64);
    if ((tid & 63) == 0) wred[tid >> 6] = v;
    __syncthreads();
    if (tid == 0)
        out[OUT_LOSS] = (wred[0] + wred[1] + wred[2] + wred[3]) * (1.25f / 4194304.f);
}

extern "C" void kernel_launch(void* const* d_in, const int* in_sizes, int n_in,
                              void* d_out, int out_size, void* d_ws, size_t ws_size,
                              hipStream_t stream) {
    const float* z   = (const float*)d_in[0];
    const float* emb = (const float*)d_in[1];
    float* out = (float*)d_out;
    float* ws  = (float*)d_ws;

    vq_sums<<<dim3((M_ + N_) / 256), dim3(256), 0, stream>>>(z, emb, ws);

    if (ws_size >= WS_NEED) {   // fast MFMA path
        char* fb = (char*)d_ws + FB_OFF;
        ull* minima = (ull*)((char*)d_ws + MIN_OFF);
        vq_prep_b<<<dim3(1024), dim3(256), 0, stream>>>(emb, fb);
        vq_mfma5<<<dim3(256), dim3(256), 0, stream>>>(z, fb, ws + WS_SZ, ws + WS_SE, minima);
        vq_pick2<<<dim3(1024), dim3(256), 0, stream>>>(z, emb, ws, minima, out);
        vq_gather<<<dim3(M_ / 64), dim3(256), 0, stream>>>(z, emb, ws + WS_PART, out);
        vq_loss<<<dim3(1), dim3(256), 0, stream>>>(ws + WS_PART, out);
    } else {                    // round-5 fallback (known-PASS)
        vq_pass1_fp32<<<dim3(M_ / 64), dim3(256), 0, stream>>>(z, emb, ws);
        vq_pass2_fp32<<<dim3(64), dim3(256), 0, stream>>>(z, emb, ws, out);
        vq_gather<<<dim3(M_ / 64), dim3(256), 0, stream>>>(z, emb, ws + O_PART, out);
        vq_loss<<<dim3(1), dim3(256), 0, stream>>>(ws + O_PART, out);
    }
}